// Round 1
// baseline (56920.496 us; speedup 1.0000x reference)
//
#include <hip/hip_runtime.h>
#include <hip/hip_bf16.h>

#define FDIM 128

// ---------- degree / norm precompute ----------

__global__ void degree_kernel(const int* __restrict__ col, int* __restrict__ deg, int E) {
    int e = blockIdx.x * blockDim.x + threadIdx.x;
    if (e < E) atomicAdd(&deg[col[e]], 1);
}

__global__ void dinv_kernel(const int* __restrict__ deg, float* __restrict__ dinv, int N) {
    int i = blockIdx.x * blockDim.x + threadIdx.x;
    if (i < N) {
        int d = deg[i];
        dinv[i] = (d > 0) ? rsqrtf((float)d) : 0.0f;
    }
}

__global__ void norm_kernel(const int* __restrict__ row, const int* __restrict__ col,
                            const float* __restrict__ dinv, float* __restrict__ nrm, int E) {
    int e = blockIdx.x * blockDim.x + threadIdx.x;
    if (e < E) nrm[e] = dinv[row[e]] * dinv[col[e]];
}

// ---------- elementwise helpers (float4-vectorized over N*F) ----------

// out = w0 * x ; bufA = 0   (w0 = mf[0], coef[0] == 1)
__global__ void init_out_kernel(const float4* __restrict__ x, const float* __restrict__ mf,
                                float4* __restrict__ out, float4* __restrict__ bufA, long n4) {
    long i = (long)blockIdx.x * blockDim.x + threadIdx.x;
    if (i < n4) {
        float w = mf[0];
        float4 v = x[i];
        out[i] = make_float4(w * v.x, w * v.y, w * v.z, w * v.w);
        bufA[i] = make_float4(0.f, 0.f, 0.f, 0.f);
    }
}

// out += w_isrc * src ; tgt = -neg_src   (neg_src may alias tgt: in-place negate)
__global__ void axpy_init_kernel(const float4* __restrict__ src, const float4* __restrict__ neg_src,
                                 float4* __restrict__ out, float4* __restrict__ tgt,
                                 const float* __restrict__ mf, const float* __restrict__ lap,
                                 int i_src, long n4) {
    long i = (long)blockIdx.x * blockDim.x + threadIdx.x;
    if (i < n4) {
        float w = mf[i_src] * lap[i_src - 1];
        float4 s = src[i];
        float4 o = out[i];
        o.x += w * s.x; o.y += w * s.y; o.z += w * s.z; o.w += w * s.w;
        out[i] = o;
        float4 ns = neg_src[i];
        tgt[i] = make_float4(-ns.x, -ns.y, -ns.z, -ns.w);
    }
}

// out += w_K * src
__global__ void final_axpy_kernel(const float4* __restrict__ src, float4* __restrict__ out,
                                  const float* __restrict__ mf, const float* __restrict__ lap,
                                  int K, long n4) {
    long i = (long)blockIdx.x * blockDim.x + threadIdx.x;
    if (i < n4) {
        float w = mf[K] * lap[K - 1];
        float4 s = src[i];
        float4 o = out[i];
        o.x += w * s.x; o.y += w * s.y; o.z += w * s.z; o.w += w * s.w;
        out[i] = o;
    }
}

// ---------- SpMM scatter: dst[col] += scale * norm * src[row] ----------
// 32 threads per edge, float4 per thread (32*4 = 128 = FDIM)

__global__ void scatter_kernel(const int* __restrict__ row, const int* __restrict__ col,
                               const float* __restrict__ nrm,
                               const float* __restrict__ src, float* __restrict__ dst,
                               float scale, long E) {
    long gid = (long)blockIdx.x * blockDim.x + threadIdx.x;
    long e = gid >> 5;
    if (e >= E) return;
    int c = (int)(gid & 31) << 2;
    int r = row[e];
    int d = col[e];
    float w = scale * nrm[e];
    float4 v = *(const float4*)(src + (long)r * FDIM + c);
    float* o = dst + (long)d * FDIM + c;
    unsafeAtomicAdd(o + 0, w * v.x);
    unsafeAtomicAdd(o + 1, w * v.y);
    unsafeAtomicAdd(o + 2, w * v.z);
    unsafeAtomicAdd(o + 3, w * v.w);
}

extern "C" void kernel_launch(void* const* d_in, const int* in_sizes, int n_in,
                              void* d_out, int out_size, void* d_ws, size_t ws_size,
                              hipStream_t stream) {
    const float* x   = (const float*)d_in[0];
    const float* mf  = (const float*)d_in[1];
    const float* lap = (const float*)d_in[2];
    const int*   ei  = (const int*)d_in[3];
    float* out = (float*)d_out;

    const int  K  = in_sizes[1] - 1;          // 10
    const long NF = (long)in_sizes[0];        // N*F
    const int  N  = (int)(NF / FDIM);         // 100000
    const int  E  = in_sizes[3] / 2;          // 3200000
    const int* row = ei;
    const int* col = ei + E;

    // workspace layout
    char* wp = (char*)d_ws;
    float* bufA = (float*)wp;  wp += NF * sizeof(float);
    float* bufB = (float*)wp;  wp += NF * sizeof(float);
    float* nrm  = (float*)wp;  wp += (size_t)E * sizeof(float);
    int*   deg  = (int*)wp;    wp += (size_t)N * sizeof(int);
    float* dinv = (float*)wp;  wp += (size_t)N * sizeof(float);

    const int BT = 256;
    const long n4 = NF / 4;
    const int n4_blocks = (int)((n4 + BT - 1) / BT);
    const int e_blocks  = (E + BT - 1) / BT;
    const int se_blocks = (int)(((long)E * 32 + BT - 1) / BT);

    // degree -> dinv -> norm
    hipMemsetAsync(deg, 0, (size_t)N * sizeof(int), stream);
    degree_kernel<<<e_blocks, BT, 0, stream>>>(col, deg, E);
    dinv_kernel<<<(N + BT - 1) / BT, BT, 0, stream>>>(deg, dinv, N);
    norm_kernel<<<e_blocks, BT, 0, stream>>>(row, col, dinv, nrm, E);

    // P0 = x : out = w0*x ; bufA = 0
    init_out_kernel<<<n4_blocks, BT, 0, stream>>>((const float4*)x, mf,
                                                  (float4*)out, (float4*)bufA, n4);
    // P1 = prop(x) -> bufA
    scatter_kernel<<<se_blocks, BT, 0, stream>>>(row, col, nrm, x, bufA, 1.0f, E);

    // P_i = 2*prop(P_{i-1}) - P_{i-2}, ping-pong bufA/bufB
    for (int i = 2; i <= K; ++i) {
        float* src = (i % 2 == 0) ? bufA : bufB;   // holds P_{i-1}
        float* tgt = (i % 2 == 0) ? bufB : bufA;   // will hold P_i
        const float* negsrc = (i == 2) ? x : (const float*)tgt;  // P_{i-2}
        // out += w_{i-1} * P_{i-1} ; tgt = -P_{i-2}
        axpy_init_kernel<<<n4_blocks, BT, 0, stream>>>((const float4*)src, (const float4*)negsrc,
                                                       (float4*)out, (float4*)tgt,
                                                       mf, lap, i - 1, n4);
        scatter_kernel<<<se_blocks, BT, 0, stream>>>(row, col, nrm, src, tgt, 2.0f, E);
    }

    // out += w_K * P_K
    float* last = (K % 2 == 0) ? bufB : bufA;
    final_axpy_kernel<<<n4_blocks, BT, 0, stream>>>((const float4*)last, (float4*)out,
                                                    mf, lap, K, n4);
}

// Round 2
// 2753.065 us; speedup vs baseline: 20.6753x; 20.6753x over previous
//
#include <hip/hip_runtime.h>
#include <hip/hip_bf16.h>

#define FDIM 128

// ---------- degree / dinv ----------

__global__ void degree_kernel(const int* __restrict__ col, int* __restrict__ deg, int E) {
    int e = blockIdx.x * blockDim.x + threadIdx.x;
    if (e < E) atomicAdd(&deg[col[e]], 1);
}

__global__ void dinv_kernel(const int* __restrict__ deg, float* __restrict__ dinv, int N) {
    int i = blockIdx.x * blockDim.x + threadIdx.x;
    if (i < N) {
        int d = deg[i];
        dinv[i] = (d > 0) ? rsqrtf((float)d) : 0.0f;
    }
}

// ---------- exclusive scan of deg -> rowptr (3-step) ----------

__global__ void scan_blocks_kernel(const int* __restrict__ deg, int* __restrict__ rowptr,
                                   int* __restrict__ bsum, int N) {
    __shared__ int s[256];
    int t = threadIdx.x;
    int i = blockIdx.x * 256 + t;
    int v = (i < N) ? deg[i] : 0;
    s[t] = v;
    __syncthreads();
    // Hillis-Steele inclusive scan
    for (int off = 1; off < 256; off <<= 1) {
        int add = (t >= off) ? s[t - off] : 0;
        __syncthreads();
        s[t] += add;
        __syncthreads();
    }
    if (i < N) rowptr[i] = s[t] - v;   // exclusive
    if (t == 255) bsum[blockIdx.x] = s[255];
}

__global__ void scan_bsums_kernel(int* __restrict__ bsum, int* __restrict__ boff, int nb) {
    __shared__ int s[512];
    int t = threadIdx.x;
    int v = (t < nb) ? bsum[t] : 0;
    s[t] = v;
    __syncthreads();
    for (int off = 1; off < 512; off <<= 1) {
        int add = (t >= off) ? s[t - off] : 0;
        __syncthreads();
        s[t] += add;
        __syncthreads();
    }
    if (t < nb) boff[t] = s[t] - v;    // exclusive
}

__global__ void add_offsets_kernel(int* __restrict__ rowptr, int* __restrict__ cursor,
                                   const int* __restrict__ boff, int N, int E) {
    int i = blockIdx.x * blockDim.x + threadIdx.x;
    if (i < N) {
        int v = rowptr[i] + boff[blockIdx.x * 256 / 256 == 0 ? blockIdx.x : blockIdx.x];
        v = rowptr[i] + boff[i >> 8];
        rowptr[i] = v;
        cursor[i] = v;
    }
    if (i == 0) rowptr[N] = E;
}

// ---------- edge placement: CSR by destination ----------
// edata[pos] = (src_row_bits, weight)

__global__ void place_kernel(const int* __restrict__ row, const int* __restrict__ col,
                             const float* __restrict__ dinv, int* __restrict__ cursor,
                             float2* __restrict__ edata, int E) {
    int e = blockIdx.x * blockDim.x + threadIdx.x;
    if (e < E) {
        int r = row[e], c = col[e];
        float w = dinv[r] * dinv[c];
        int pos = atomicAdd(&cursor[c], 1);
        edata[pos] = make_float2(__int_as_float(r), w);
    }
}

// ---------- out = mf[0] * x ----------

__global__ void init_out_kernel(const float4* __restrict__ x, const float* __restrict__ mf,
                                float4* __restrict__ out, long n4) {
    long i = (long)blockIdx.x * blockDim.x + threadIdx.x;
    if (i < n4) {
        float w = mf[0];
        float4 v = x[i];
        out[i] = make_float4(w * v.x, w * v.y, w * v.z, w * v.w);
    }
}

// ---------- fused gather prop ----------
// one wave per node; lane holds float2 slice of F=128
// tgt[n] = scale * sum_e w_e * src[idx_e]  +  beta * prev2[n]
// out[n] += coef_i * tgt[n]      (coef_i = mf[i] * lap[i-1])

__global__ __launch_bounds__(256) void gather_prop_kernel(
        const float2* __restrict__ edata, const int* __restrict__ rowptr,
        const float* __restrict__ src, const float* __restrict__ prev2,
        float* __restrict__ tgt, float* __restrict__ out,
        const float* __restrict__ mf, const float* __restrict__ lap,
        int i_coef, float scale, float beta, int N) {
    int wid = blockIdx.x * 4 + (threadIdx.x >> 6);
    if (wid >= N) return;
    int lane = threadIdx.x & 63;
    int begin = rowptr[wid];
    int end = rowptr[wid + 1];
    float accx = 0.f, accy = 0.f;
    int laneoff = lane << 1;
    #pragma unroll 4
    for (int e = begin; e < end; ++e) {
        float2 ed = edata[e];
        int idx = __float_as_int(ed.x);
        float w = ed.y;
        const float2 v = *(const float2*)(src + ((long)idx << 7) + laneoff);
        accx += w * v.x;
        accy += w * v.y;
    }
    float coef = mf[i_coef] * lap[i_coef - 1];
    long o = ((long)wid << 7) + laneoff;
    float2 p = *(const float2*)(prev2 + o);
    float tx = scale * accx + beta * p.x;
    float ty = scale * accy + beta * p.y;
    *(float2*)(tgt + o) = make_float2(tx, ty);
    float2 ov = *(const float2*)(out + o);
    ov.x += coef * tx;
    ov.y += coef * ty;
    *(float2*)(out + o) = ov;
}

extern "C" void kernel_launch(void* const* d_in, const int* in_sizes, int n_in,
                              void* d_out, int out_size, void* d_ws, size_t ws_size,
                              hipStream_t stream) {
    const float* x   = (const float*)d_in[0];
    const float* mf  = (const float*)d_in[1];
    const float* lap = (const float*)d_in[2];
    const int*   ei  = (const int*)d_in[3];
    float* out = (float*)d_out;

    const int  K  = in_sizes[1] - 1;          // 10
    const long NF = (long)in_sizes[0];        // N*F
    const int  N  = (int)(NF / FDIM);         // 100000
    const int  E  = in_sizes[3] / 2;          // 3200000
    const int* row = ei;
    const int* col = ei + E;

    // workspace layout
    char* wp = (char*)d_ws;
    float*  bufA   = (float*)wp;  wp += NF * sizeof(float);
    float*  bufB   = (float*)wp;  wp += NF * sizeof(float);
    float2* edata  = (float2*)wp; wp += (size_t)E * sizeof(float2);
    int*    rowptr = (int*)wp;    wp += (size_t)(N + 1) * sizeof(int);
    int*    cursor = (int*)wp;    wp += (size_t)N * sizeof(int);
    int*    deg    = (int*)wp;    wp += (size_t)N * sizeof(int);
    float*  dinv   = (float*)wp;  wp += (size_t)N * sizeof(float);
    int*    bsum   = (int*)wp;    wp += 512 * sizeof(int);
    int*    boff   = (int*)wp;    wp += 512 * sizeof(int);

    const int BT = 256;
    const long n4 = NF / 4;
    const int n4_blocks = (int)((n4 + BT - 1) / BT);
    const int e_blocks  = (E + BT - 1) / BT;
    const int n_blocks  = (N + BT - 1) / BT;   // also = #scan blocks (391)

    // CSR build
    hipMemsetAsync(deg, 0, (size_t)N * sizeof(int), stream);
    degree_kernel<<<e_blocks, BT, 0, stream>>>(col, deg, E);
    dinv_kernel<<<n_blocks, BT, 0, stream>>>(deg, dinv, N);
    scan_blocks_kernel<<<n_blocks, BT, 0, stream>>>(deg, rowptr, bsum, N);
    scan_bsums_kernel<<<1, 512, 0, stream>>>(bsum, boff, n_blocks);
    add_offsets_kernel<<<n_blocks, BT, 0, stream>>>(rowptr, cursor, boff, N, E);
    place_kernel<<<e_blocks, BT, 0, stream>>>(row, col, dinv, cursor, edata, E);

    // out = mf0 * x
    init_out_kernel<<<n4_blocks, BT, 0, stream>>>((const float4*)x, mf, (float4*)out, n4);

    const int g_blocks = (N + 3) / 4;   // one wave per node, 4 waves/block

    // P1 = prop(x) -> bufA ; out += c1*P1
    gather_prop_kernel<<<g_blocks, BT, 0, stream>>>(edata, rowptr, x, x,
                                                    bufA, out, mf, lap,
                                                    1, 1.0f, 0.0f, N);
    // P_i = 2*prop(P_{i-1}) - P_{i-2} ; out += c_i*P_i
    // targets: P2->bufB, P3->bufA(over P1), P4->bufB(over P2), ...
    for (int i = 2; i <= K; ++i) {
        const float* src   = (i % 2 == 0) ? bufA : bufB;   // P_{i-1}
        float*       tgt   = (i % 2 == 0) ? bufB : bufA;   // P_i (overwrites P_{i-2})
        const float* prev2 = (i == 2) ? x : (const float*)tgt;
        gather_prop_kernel<<<g_blocks, BT, 0, stream>>>(edata, rowptr, src, prev2,
                                                        tgt, out, mf, lap,
                                                        i, 2.0f, -1.0f, N);
    }
}

// Round 3
// 1931.854 us; speedup vs baseline: 29.4642x; 1.4251x over previous
//
#include <hip/hip_runtime.h>
#include <hip/hip_bf16.h>
#include <hip/hip_fp16.h>

#define FDIM 128

// ---------- degree / dinv ----------

__global__ void degree_kernel(const int* __restrict__ col, int* __restrict__ deg, int E) {
    int e = blockIdx.x * blockDim.x + threadIdx.x;
    if (e < E) atomicAdd(&deg[col[e]], 1);
}

__global__ void dinv_kernel(const int* __restrict__ deg, float* __restrict__ dinv, int N) {
    int i = blockIdx.x * blockDim.x + threadIdx.x;
    if (i < N) {
        int d = deg[i];
        dinv[i] = (d > 0) ? rsqrtf((float)d) : 0.0f;
    }
}

// ---------- exclusive scan of deg -> rowptr ----------

__global__ void scan_blocks_kernel(const int* __restrict__ deg, int* __restrict__ rowptr,
                                   int* __restrict__ bsum, int N) {
    __shared__ int s[256];
    int t = threadIdx.x;
    int i = blockIdx.x * 256 + t;
    int v = (i < N) ? deg[i] : 0;
    s[t] = v;
    __syncthreads();
    for (int off = 1; off < 256; off <<= 1) {
        int add = (t >= off) ? s[t - off] : 0;
        __syncthreads();
        s[t] += add;
        __syncthreads();
    }
    if (i < N) rowptr[i] = s[t] - v;
    if (t == 255) bsum[blockIdx.x] = s[255];
}

__global__ void scan_bsums_kernel(int* __restrict__ bsum, int* __restrict__ boff, int nb) {
    __shared__ int s[512];
    int t = threadIdx.x;
    int v = (t < nb) ? bsum[t] : 0;
    s[t] = v;
    __syncthreads();
    for (int off = 1; off < 512; off <<= 1) {
        int add = (t >= off) ? s[t - off] : 0;
        __syncthreads();
        s[t] += add;
        __syncthreads();
    }
    if (t < nb) boff[t] = s[t] - v;
}

__global__ void add_offsets_kernel(int* __restrict__ rowptr, int* __restrict__ cursor,
                                   const int* __restrict__ boff, int N, int E) {
    int i = blockIdx.x * blockDim.x + threadIdx.x;
    if (i < N) {
        int v = rowptr[i] + boff[i >> 8];
        rowptr[i] = v;
        cursor[i] = v;
    }
    if (i == 0) rowptr[N] = E;
}

// ---------- edge placement: CSR by destination ----------

__global__ void place_kernel(const int* __restrict__ row, const int* __restrict__ col,
                             const float* __restrict__ dinv, int* __restrict__ cursor,
                             float2* __restrict__ edata, int E) {
    int e = blockIdx.x * blockDim.x + threadIdx.x;
    if (e < E) {
        int r = row[e], c = col[e];
        float w = dinv[r] * dinv[c];
        int pos = atomicAdd(&cursor[c], 1);
        edata[pos] = make_float2(__int_as_float(r), w);
    }
}

// ---------- out = mf[0] * x ----------

__global__ void init_out_kernel(const float4* __restrict__ x, const float* __restrict__ mf,
                                float4* __restrict__ out, long n4) {
    long i = (long)blockIdx.x * blockDim.x + threadIdx.x;
    if (i < n4) {
        float w = mf[0];
        float4 v = x[i];
        out[i] = make_float4(w * v.x, w * v.y, w * v.z, w * v.w);
    }
}

// ---------- fused gather prop ----------
// one wave per dst node; lane holds 2-elem slice of F=128
// tgt[n]  = scale * sum_e w_e * src[idx_e]  +  beta * prev2[n]   (fp32 state)
// tgth[n] = fp16(tgt[n])                                         (gather shadow)
// out[n] += coef_i * tgt[n]

template <typename ST>
__global__ __launch_bounds__(256) void gather_prop_kernel(
        const float2* __restrict__ edata, const int* __restrict__ rowptr,
        const ST* __restrict__ src, const float* __restrict__ prev2,
        float* __restrict__ tgt, __half* __restrict__ tgth, float* __restrict__ out,
        const float* __restrict__ mf, const float* __restrict__ lap,
        int i_coef, float scale, float beta, int N) {
    int wid = blockIdx.x * 4 + (threadIdx.x >> 6);
    if (wid >= N) return;
    int lane = threadIdx.x & 63;
    int begin = rowptr[wid];
    int end = rowptr[wid + 1];
    float accx = 0.f, accy = 0.f;
    int laneoff = lane << 1;
    #pragma unroll 4
    for (int e = begin; e < end; ++e) {
        float2 ed = edata[e];
        int idx = __float_as_int(ed.x);
        float w = ed.y;
        float vx, vy;
        if constexpr (sizeof(ST) == 4) {
            const float2 v = *(const float2*)(src + ((long)idx << 7) + laneoff);
            vx = v.x; vy = v.y;
        } else {
            const __half2 v = *(const __half2*)(src + ((long)idx << 7) + laneoff);
            float2 vf = __half22float2(v);
            vx = vf.x; vy = vf.y;
        }
        accx += w * vx;
        accy += w * vy;
    }
    float coef = mf[i_coef] * lap[i_coef - 1];
    long o = ((long)wid << 7) + laneoff;
    float2 p = *(const float2*)(prev2 + o);
    float tx = scale * accx + beta * p.x;
    float ty = scale * accy + beta * p.y;
    *(float2*)(tgt + o) = make_float2(tx, ty);
    if (tgth) *(__half2*)(tgth + o) = __floats2half2_rn(tx, ty);
    float2 ov = *(const float2*)(out + o);
    ov.x += coef * tx;
    ov.y += coef * ty;
    *(float2*)(out + o) = ov;
}

extern "C" void kernel_launch(void* const* d_in, const int* in_sizes, int n_in,
                              void* d_out, int out_size, void* d_ws, size_t ws_size,
                              hipStream_t stream) {
    const float* x   = (const float*)d_in[0];
    const float* mf  = (const float*)d_in[1];
    const float* lap = (const float*)d_in[2];
    const int*   ei  = (const int*)d_in[3];
    float* out = (float*)d_out;

    const int  K  = in_sizes[1] - 1;          // 10
    const long NF = (long)in_sizes[0];        // N*F
    const int  N  = (int)(NF / FDIM);         // 100000
    const int  E  = in_sizes[3] / 2;          // 3200000
    const int* row = ei;
    const int* col = ei + E;

    // workspace layout (~180 MB)
    char* wp = (char*)d_ws;
    float*  bufA   = (float*)wp;  wp += NF * sizeof(float);
    float*  bufB   = (float*)wp;  wp += NF * sizeof(float);
    __half* hbufA  = (__half*)wp; wp += NF * sizeof(__half);
    __half* hbufB  = (__half*)wp; wp += NF * sizeof(__half);
    float2* edata  = (float2*)wp; wp += (size_t)E * sizeof(float2);
    int*    rowptr = (int*)wp;    wp += (size_t)(N + 1) * sizeof(int);
    int*    cursor = (int*)wp;    wp += (size_t)N * sizeof(int);
    int*    deg    = (int*)wp;    wp += (size_t)N * sizeof(int);
    float*  dinv   = (float*)wp;  wp += (size_t)N * sizeof(float);
    int*    bsum   = (int*)wp;    wp += 512 * sizeof(int);
    int*    boff   = (int*)wp;    wp += 512 * sizeof(int);

    const int BT = 256;
    const long n4 = NF / 4;
    const int n4_blocks = (int)((n4 + BT - 1) / BT);
    const int e_blocks  = (E + BT - 1) / BT;
    const int n_blocks  = (N + BT - 1) / BT;

    // CSR build
    hipMemsetAsync(deg, 0, (size_t)N * sizeof(int), stream);
    degree_kernel<<<e_blocks, BT, 0, stream>>>(col, deg, E);
    dinv_kernel<<<n_blocks, BT, 0, stream>>>(deg, dinv, N);
    scan_blocks_kernel<<<n_blocks, BT, 0, stream>>>(deg, rowptr, bsum, N);
    scan_bsums_kernel<<<1, 512, 0, stream>>>(bsum, boff, n_blocks);
    add_offsets_kernel<<<n_blocks, BT, 0, stream>>>(rowptr, cursor, boff, N, E);
    place_kernel<<<e_blocks, BT, 0, stream>>>(row, col, dinv, cursor, edata, E);

    // out = mf0 * x
    init_out_kernel<<<n4_blocks, BT, 0, stream>>>((const float4*)x, mf, (float4*)out, n4);

    const int g_blocks = (N + 3) / 4;

    // P1 = prop(x) -> bufA (+hbufA) ; out += c1*P1   (gathers fp32 x directly)
    gather_prop_kernel<float><<<g_blocks, BT, 0, stream>>>(edata, rowptr, x, x,
                                                           bufA, hbufA, out, mf, lap,
                                                           1, 1.0f, 0.0f, N);
    // P_i = 2*prop(P_{i-1}) - P_{i-2} ; out += c_i*P_i   (gathers fp16 shadow)
    for (int i = 2; i <= K; ++i) {
        const __half* srch  = (i % 2 == 0) ? hbufA : hbufB;  // fp16(P_{i-1})
        float*        tgt   = (i % 2 == 0) ? bufB : bufA;    // P_i (overwrites P_{i-2})
        __half*       tgth  = (i % 2 == 0) ? hbufB : hbufA;
        const float*  prev2 = (i == 2) ? x : (const float*)tgt;
        if (i == K) tgth = nullptr;  // last shadow never gathered
        gather_prop_kernel<__half><<<g_blocks, BT, 0, stream>>>(edata, rowptr, srch, prev2,
                                                                tgt, tgth, out, mf, lap,
                                                                i, 2.0f, -1.0f, N);
    }
}